// Round 1
// baseline (3761.679 us; speedup 1.0000x reference)
//
#include <hip/hip_runtime.h>

// PointerNetwork: B=64, N=512, E=512, 2E=1024, T=64 decode steps.
// Structure:
//   kenc (once): enc[b,n,e] = TE[b,n,:]·We[e,:] + be[e]   (f32 tiled GEMM, 34.4 GF)
//   per step t (3 launches):
//     kstep_hx: [fused] softmax/argmax of prev scores -> logp row write + idx
//               + gather x=TE[b,idx[b]] (t=0: encoded_document)
//               + gates = x@W_ih^T (+biases, f-gate skipped) -> hx   (256 blocks)
//     kq      : q = hx@Wd^T + bd                                     (128 blocks)
//     kscore  : scores[b,n] = sum_e wr[e]*tanh(q[b,e]+enc[b,n,e])+br (512 blocks)
//   kfin (once): softmax/argmax for step 63 outputs.
// All f32 (argmax chain is precision-critical). Indices written as float.

#define DEV __device__ __forceinline__

DEV float sigm(float x) { return __fdividef(1.0f, 1.0f + __expf(-x)); }
DEV float tanh_fast(float x) {
  float e = __expf(2.0f * x);                 // exact identity tanh = 1 - 2/(e^2x+1)
  return 1.0f - __fdividef(2.0f, e + 1.0f);   // inf-safe at both ends
}

#define FMA4(acc, xv, wv)                                                      \
  acc = fmaf((xv).x, (wv).x, acc); acc = fmaf((xv).y, (wv).y, acc);            \
  acc = fmaf((xv).z, (wv).z, acc); acc = fmaf((xv).w, (wv).w, acc)

// ---------------- enc GEMM: C[32768x512] = A[32768x1024] @ B[512x1024]^T + bias
__global__ __launch_bounds__(256) void kenc(const float* __restrict__ A,
                                            const float* __restrict__ Bm,
                                            const float* __restrict__ bias,
                                            float* __restrict__ C) {
  __shared__ float a_s[16][132];
  __shared__ float b_s[16][132];
  const int t = threadIdx.x;
  const int row = t >> 1;            // 0..127
  const int kq = (t & 1) * 8;        // 0 or 8
  const float* Arow = A + (blockIdx.x * 128 + row) * 1024 + kq;
  const float* Brow = Bm + (blockIdx.y * 128 + row) * 1024 + kq;
  const int tx = t & 15, ty = t >> 4;
  float acc[8][8] = {};
  for (int k0 = 0; k0 < 1024; k0 += 16) {
    float4 av0 = *(const float4*)(Arow + k0);
    float4 av1 = *(const float4*)(Arow + k0 + 4);
    float4 bv0 = *(const float4*)(Brow + k0);
    float4 bv1 = *(const float4*)(Brow + k0 + 4);
    __syncthreads();
    a_s[kq+0][row]=av0.x; a_s[kq+1][row]=av0.y; a_s[kq+2][row]=av0.z; a_s[kq+3][row]=av0.w;
    a_s[kq+4][row]=av1.x; a_s[kq+5][row]=av1.y; a_s[kq+6][row]=av1.z; a_s[kq+7][row]=av1.w;
    b_s[kq+0][row]=bv0.x; b_s[kq+1][row]=bv0.y; b_s[kq+2][row]=bv0.z; b_s[kq+3][row]=bv0.w;
    b_s[kq+4][row]=bv1.x; b_s[kq+5][row]=bv1.y; b_s[kq+6][row]=bv1.z; b_s[kq+7][row]=bv1.w;
    __syncthreads();
    #pragma unroll
    for (int k = 0; k < 16; ++k) {
      float a[8], b[8];
      *(float4*)(a)   = *(const float4*)&a_s[k][ty*8];
      *(float4*)(a+4) = *(const float4*)&a_s[k][ty*8+4];
      *(float4*)(b)   = *(const float4*)&b_s[k][tx*8];
      *(float4*)(b+4) = *(const float4*)&b_s[k][tx*8+4];
      #pragma unroll
      for (int i = 0; i < 8; ++i)
        #pragma unroll
        for (int j = 0; j < 8; ++j)
          acc[i][j] = fmaf(a[i], b[j], acc[i][j]);
    }
  }
  const int mb = blockIdx.x * 128 + ty * 8;
  const int eb = blockIdx.y * 128 + tx * 8;
  float bv[8];
  #pragma unroll
  for (int j = 0; j < 8; ++j) bv[j] = bias[eb + j];
  #pragma unroll
  for (int i = 0; i < 8; ++i) {
    float* orow = C + (mb + i) * 512 + eb;
    float4 o0, o1;
    o0.x=acc[i][0]+bv[0]; o0.y=acc[i][1]+bv[1]; o0.z=acc[i][2]+bv[2]; o0.w=acc[i][3]+bv[3];
    o1.x=acc[i][4]+bv[4]; o1.y=acc[i][5]+bv[5]; o1.z=acc[i][6]+bv[6]; o1.w=acc[i][7]+bv[7];
    *(float4*)orow = o0; *(float4*)(orow + 4) = o1;
  }
}

// ---------------- per-step: fused softmax(prev)+gather+gates->hx
// grid 256 blocks x 256 thr. Block g owns hx columns k0=2g, k1=2g+1.
// Wave wu (0..3) covers d in [wu*256, wu*256+256), all 64 batches (lane=b).
__global__ __launch_bounds__(256) void kstep_hx(
    const float* __restrict__ TE, const float* __restrict__ encd,
    const float* __restrict__ W_ih, const float* __restrict__ b_ih,
    const float* __restrict__ b_hh, const float* __restrict__ scores,
    float* __restrict__ hx, float* __restrict__ out_logp,
    float* __restrict__ out_idx, int step) {
  __shared__ int   idx_s[64];
  __shared__ float mx_s[64];
  __shared__ float wsum_s[4];
  __shared__ float part_s[4][64][6];
  const int g = blockIdx.x;
  const int t = threadIdx.x;
  const int lane = t & 63;
  const int wu = __builtin_amdgcn_readfirstlane(t >> 6);

  // A: argmax of previous step's scores (all blocks need all 64 idx for gather)
  if (step > 0) {
    const int row = t >> 2, qq = t & 3;
    const float* srow = scores + row * 512;
    float bv = -3.0e38f; int bi = 0;
    #pragma unroll 8
    for (int n = qq; n < 512; n += 4) {
      float s = srow[n];
      if (s > bv) { bv = s; bi = n; }   // strictly > keeps first occurrence
    }
    #pragma unroll
    for (int m = 1; m <= 2; m <<= 1) {  // combine the 4 stride-classes
      float ov = __shfl_xor(bv, m);
      int   oi = __shfl_xor(bi, m);
      if (ov > bv || (ov == bv && oi < bi)) { bv = ov; bi = oi; }
    }
    if (qq == 0) { idx_s[row] = bi; mx_s[row] = bv; }
  }
  __syncthreads();

  // B/C: blocks 0..63 compute logsumexp + write logp row + idx for step-1
  if (step > 0 && g < 64) {
    const float* srow = scores + g * 512;
    const float mx = mx_s[g];
    float ssum = __expf(srow[t] - mx) + __expf(srow[t + 256] - mx);
    #pragma unroll
    for (int m = 1; m <= 32; m <<= 1) ssum += __shfl_xor(ssum, m);
    if (lane == 0) wsum_s[wu] = ssum;
  }
  __syncthreads();
  if (step > 0 && g < 64) {
    const float* srow = scores + g * 512;
    const float lse = mx_s[g] + __logf(wsum_s[0] + wsum_s[1] + wsum_s[2] + wsum_s[3]);
    float* orow = out_logp + (g * 64 + (step - 1)) * 512;
    orow[t]       = srow[t]       - lse;
    orow[t + 256] = srow[t + 256] - lse;
    if (t == 0) out_idx[g * 64 + (step - 1)] = (float)idx_s[g];
  }

  // D: gates GEMM slice (i,g,o gates only; f-gate is dead: c_prev = 0)
  const int k0 = 2 * g, k1 = 2 * g + 1;
  const int dbase = wu * 256;
  const float* p0 = W_ih + (k0        ) * 1024 + dbase;
  const float* p1 = W_ih + (k1        ) * 1024 + dbase;
  const float* p2 = W_ih + (1024 + k0) * 1024 + dbase;
  const float* p3 = W_ih + (1024 + k1) * 1024 + dbase;
  const float* p4 = W_ih + (1536 + k0) * 1024 + dbase;
  const float* p5 = W_ih + (1536 + k1) * 1024 + dbase;
  const float* xr = (step == 0) ? (encd + lane * 1024 + dbase)
                                : (TE + (lane * 512 + idx_s[lane]) * 1024 + dbase);
  float a0=0, a1=0, a2=0, a3=0, a4=0, a5=0;
  #pragma unroll 4
  for (int d = 0; d < 256; d += 4) {
    float4 xv = *(const float4*)(xr + d);
    float4 v0 = *(const float4*)(p0 + d);
    float4 v1 = *(const float4*)(p1 + d);
    float4 v2 = *(const float4*)(p2 + d);
    float4 v3 = *(const float4*)(p3 + d);
    float4 v4 = *(const float4*)(p4 + d);
    float4 v5 = *(const float4*)(p5 + d);
    FMA4(a0, xv, v0); FMA4(a1, xv, v1); FMA4(a2, xv, v2);
    FMA4(a3, xv, v3); FMA4(a4, xv, v4); FMA4(a5, xv, v5);
  }
  part_s[wu][lane][0]=a0; part_s[wu][lane][1]=a1; part_s[wu][lane][2]=a2;
  part_s[wu][lane][3]=a3; part_s[wu][lane][4]=a4; part_s[wu][lane][5]=a5;
  __syncthreads();

  // E: combine d-quarters, add biases, LSTM activations, write hx
  if (t < 64) {
    float s0=0, s1=0, s2=0, s3=0, s4=0, s5=0;
    #pragma unroll
    for (int u = 0; u < 4; ++u) {
      s0 += part_s[u][t][0]; s1 += part_s[u][t][1]; s2 += part_s[u][t][2];
      s3 += part_s[u][t][3]; s4 += part_s[u][t][4]; s5 += part_s[u][t][5];
    }
    const float gi0 = s0 + b_ih[k0] + b_hh[k0];
    const float gi1 = s1 + b_ih[k1] + b_hh[k1];
    const float gg0 = s2 + b_ih[1024 + k0] + b_hh[1024 + k0];
    const float gg1 = s3 + b_ih[1024 + k1] + b_hh[1024 + k1];
    const float go0 = s4 + b_ih[1536 + k0] + b_hh[1536 + k0];
    const float go1 = s5 + b_ih[1536 + k1] + b_hh[1536 + k1];
    const float c0 = sigm(gi0) * tanh_fast(gg0);
    const float c1 = sigm(gi1) * tanh_fast(gg1);
    hx[t * 512 + k0] = sigm(go0) * tanh_fast(c0);
    hx[t * 512 + k1] = sigm(go1) * tanh_fast(c1);
  }
}

// ---------------- q = hx @ Wd^T + bd. grid 128 blocks; block owns e = 4g..4g+3.
__global__ __launch_bounds__(256) void kq(const float* __restrict__ hx,
                                          const float* __restrict__ Wd,
                                          const float* __restrict__ bd,
                                          float* __restrict__ q) {
  __shared__ float part_s[4][64][4];
  const int g = blockIdx.x;
  const int t = threadIdx.x, lane = t & 63;
  const int wu = __builtin_amdgcn_readfirstlane(t >> 6);
  const int dbase = wu * 128;
  const int e0 = g * 4;
  const float* w0 = Wd + (e0 + 0) * 512 + dbase;
  const float* w1 = Wd + (e0 + 1) * 512 + dbase;
  const float* w2 = Wd + (e0 + 2) * 512 + dbase;
  const float* w3 = Wd + (e0 + 3) * 512 + dbase;
  const float* xr = hx + lane * 512 + dbase;
  float a0=0, a1=0, a2=0, a3=0;
  #pragma unroll 8
  for (int d = 0; d < 128; d += 4) {
    float4 xv = *(const float4*)(xr + d);
    float4 v0 = *(const float4*)(w0 + d);
    float4 v1 = *(const float4*)(w1 + d);
    float4 v2 = *(const float4*)(w2 + d);
    float4 v3 = *(const float4*)(w3 + d);
    FMA4(a0, xv, v0); FMA4(a1, xv, v1); FMA4(a2, xv, v2); FMA4(a3, xv, v3);
  }
  part_s[wu][lane][0]=a0; part_s[wu][lane][1]=a1;
  part_s[wu][lane][2]=a2; part_s[wu][lane][3]=a3;
  __syncthreads();
  if (t < 64) {
    float4 r;
    r.x = part_s[0][t][0]+part_s[1][t][0]+part_s[2][t][0]+part_s[3][t][0] + bd[e0+0];
    r.y = part_s[0][t][1]+part_s[1][t][1]+part_s[2][t][1]+part_s[3][t][1] + bd[e0+1];
    r.z = part_s[0][t][2]+part_s[1][t][2]+part_s[2][t][2]+part_s[3][t][2] + bd[e0+2];
    r.w = part_s[0][t][3]+part_s[1][t][3]+part_s[2][t][3]+part_s[3][t][3] + bd[e0+3];
    *(float4*)(q + t * 512 + e0) = r;
  }
}

// ---------------- scores[b,n] = sum_e wr[e]*tanh(q[b,e]+enc[b,n,e]) + br
// grid 512 blocks: b = bid>>3, n-chunk = bid&7 (64 n each).
// Per wave-iter: 4 n in parallel (lane>>4 picks n), 16 lanes split e (32 e each).
__global__ __launch_bounds__(256) void kscore(const float* __restrict__ enc,
                                              const float* __restrict__ q,
                                              const float* __restrict__ wr,
                                              const float* __restrict__ br,
                                              float* __restrict__ scores) {
  const int bid = blockIdx.x;
  const int b = bid >> 3, c = bid & 7;
  const int t = threadIdx.x, lane = t & 63, w = t >> 6;
  const int le = lane & 15, nl = lane >> 4;
  float4 qv[8], wv[8];
  const float* qrow = q + b * 512 + le * 4;
  const float* wrp  = wr + le * 4;
  #pragma unroll
  for (int j = 0; j < 8; ++j) {
    qv[j] = *(const float4*)(qrow + 64 * j);
    wv[j] = *(const float4*)(wrp  + 64 * j);
  }
  const float brv = br[0];
  #pragma unroll
  for (int i = 0; i < 4; ++i) {
    const int n = c * 64 + w * 16 + i * 4 + nl;
    const float* erow = enc + (b * 512 + n) * 512 + le * 4;
    float acc = 0.0f;
    #pragma unroll
    for (int j = 0; j < 8; ++j) {
      float4 ev = *(const float4*)(erow + 64 * j);
      acc += wv[j].x * tanh_fast(qv[j].x + ev.x);
      acc += wv[j].y * tanh_fast(qv[j].y + ev.y);
      acc += wv[j].z * tanh_fast(qv[j].z + ev.z);
      acc += wv[j].w * tanh_fast(qv[j].w + ev.w);
    }
    acc += __shfl_xor(acc, 1);
    acc += __shfl_xor(acc, 2);
    acc += __shfl_xor(acc, 4);
    acc += __shfl_xor(acc, 8);
    if (le == 0) scores[b * 512 + n] = acc + brv;
  }
}

// ---------------- final-step softmax/argmax (writes t=63 outputs)
__global__ __launch_bounds__(256) void kfin(const float* __restrict__ scores,
                                            float* __restrict__ out_logp,
                                            float* __restrict__ out_idx) {
  __shared__ float mxw[4]; __shared__ int idw[4]; __shared__ float sw[4];
  const int b = blockIdx.x, t = threadIdx.x, lane = t & 63, w = t >> 6;
  const float* srow = scores + b * 512;
  const float s1 = srow[t], s2 = srow[t + 256];
  float bv; int bi;
  if (s1 >= s2) { bv = s1; bi = t; } else { bv = s2; bi = t + 256; }
  #pragma unroll
  for (int m = 1; m <= 32; m <<= 1) {
    float ov = __shfl_xor(bv, m);
    int   oi = __shfl_xor(bi, m);
    if (ov > bv || (ov == bv && oi < bi)) { bv = ov; bi = oi; }
  }
  if (lane == 0) { mxw[w] = bv; idw[w] = bi; }
  __syncthreads();
  float mx = mxw[0]; int mi = idw[0];
  #pragma unroll
  for (int u = 1; u < 4; ++u)
    if (mxw[u] > mx || (mxw[u] == mx && idw[u] < mi)) { mx = mxw[u]; mi = idw[u]; }
  float ssum = __expf(s1 - mx) + __expf(s2 - mx);
  #pragma unroll
  for (int m = 1; m <= 32; m <<= 1) ssum += __shfl_xor(ssum, m);
  if (lane == 0) sw[w] = ssum;
  __syncthreads();
  const float lse = mx + __logf(sw[0] + sw[1] + sw[2] + sw[3]);
  float* orow = out_logp + (b * 64 + 63) * 512;
  orow[t]       = s1 - lse;
  orow[t + 256] = s2 - lse;
  if (t == 0) out_idx[b * 64 + 63] = (float)mi;
}

extern "C" void kernel_launch(void* const* d_in, const int* in_sizes, int n_in,
                              void* d_out, int out_size, void* d_ws, size_t ws_size,
                              hipStream_t stream) {
  const float* TE   = (const float*)d_in[0];   // [64,512,1024]
  const float* encd = (const float*)d_in[1];   // [64,1024]
  const float* W_ih = (const float*)d_in[2];   // [2048,1024]
  const float* b_ih = (const float*)d_in[3];   // [2048]
  const float* b_hh = (const float*)d_in[4];   // [2048]
  const float* Wd   = (const float*)d_in[5];   // [512,512]
  const float* bd   = (const float*)d_in[6];   // [512]
  const float* We   = (const float*)d_in[7];   // [512,1024]
  const float* be   = (const float*)d_in[8];   // [512]
  const float* wr   = (const float*)d_in[9];   // [512]
  const float* br   = (const float*)d_in[10];  // [1]

  float* out     = (float*)d_out;              // logp [64][64][512]
  float* out_idx = out + 64 * 64 * 512;        // indices as float [64][64]

  float* enc    = (float*)d_ws;                // 16,777,216 f (64 MB)
  float* scores = enc + 16777216;              // 32,768 f
  float* hx     = scores + 32768;              // 32,768 f
  float* q      = hx + 32768;                  // 32,768 f

  kenc<<<dim3(256, 4), 256, 0, stream>>>(TE, We, be, enc);
  for (int t = 0; t < 64; ++t) {
    kstep_hx<<<256, 256, 0, stream>>>(TE, encd, W_ih, b_ih, b_hh, scores, hx,
                                      out, out_idx, t);
    kq<<<128, 256, 0, stream>>>(hx, Wd, bd, q);
    kscore<<<512, 256, 0, stream>>>(enc, q, wr, br, scores);
  }
  kfin<<<64, 256, 0, stream>>>(scores, out, out_idx);
}